// Round 2
// baseline (274.748 us; speedup 1.0000x reference)
//
#include <hip/hip_runtime.h>

#define N_NODES 100000
#define N_EDGES 1600000
#define IN_F 32
#define HID_F 64
#define OUT_F 16
#define CAPN 48                      // per-node edge capacity (Poisson(16); P(deg>=48)~5e-11, guarded)
#define APITCH 68                    // padded pitch for transposed A / h1 tiles

using f2v = __attribute__((ext_vector_type(2))) float;

// accumulate 16 fp8-e4m3 (packed in uint4 Q, HW decode) into 16 fp32 accumulators
#define ADDQ(s, Q) do { f2v p_; \
  p_ = __builtin_amdgcn_cvt_pk_f32_fp8((int)(Q).x, false); s[0] += p_[0]; s[1] += p_[1]; \
  p_ = __builtin_amdgcn_cvt_pk_f32_fp8((int)(Q).x, true);  s[2] += p_[0]; s[3] += p_[1]; \
  p_ = __builtin_amdgcn_cvt_pk_f32_fp8((int)(Q).y, false); s[4] += p_[0]; s[5] += p_[1]; \
  p_ = __builtin_amdgcn_cvt_pk_f32_fp8((int)(Q).y, true);  s[6] += p_[0]; s[7] += p_[1]; \
  p_ = __builtin_amdgcn_cvt_pk_f32_fp8((int)(Q).z, false); s[8] += p_[0]; s[9] += p_[1]; \
  p_ = __builtin_amdgcn_cvt_pk_f32_fp8((int)(Q).z, true);  s[10] += p_[0]; s[11] += p_[1]; \
  p_ = __builtin_amdgcn_cvt_pk_f32_fp8((int)(Q).w, false); s[12] += p_[0]; s[13] += p_[1]; \
  p_ = __builtin_amdgcn_cvt_pk_f32_fp8((int)(Q).w, true);  s[14] += p_[0]; s[15] += p_[1]; \
} while (0)

// ---------------- zero the per-node degree counters (400 KB) ----------------
__global__ __launch_bounds__(256) void zero_cnt_kernel(uint4* __restrict__ cnt4) {
  int i = blockIdx.x * 256 + threadIdx.x;
  if (i < N_NODES / 4) cnt4[i] = make_uint4(0u, 0u, 0u, 0u);
}

// ---------------- scatter CSR build (scan-free, fixed-capacity arena) ----------------
// col[d*CAPN + atomicAdd(&cnt[d],1)] = s.  Also absorbs feat -> fp8 e4m3 conversion
// (independent work that hides atomic/scatter latency).
__global__ __launch_bounds__(256) void scatter_kernel(
    const int4* __restrict__ src4, const int4* __restrict__ dst4,
    const float4* __restrict__ featin,
    int* __restrict__ cnt, int* __restrict__ col, uint4* __restrict__ featfp8) {
  int gtid = blockIdx.x * 256 + threadIdx.x;

  // ---- absorbed conversion: feat -> fp8 e4m3 (16 floats per thread) ----
  if (gtid < N_NODES * IN_F / 16) {
    float4 a = featin[4 * gtid], bb = featin[4 * gtid + 1];
    float4 c4 = featin[4 * gtid + 2], d = featin[4 * gtid + 3];
    uint4 r;
    int w;
    w = __builtin_amdgcn_cvt_pk_fp8_f32(a.x, a.y, 0, false);
    w = __builtin_amdgcn_cvt_pk_fp8_f32(a.z, a.w, w, true);
    r.x = (unsigned)w;
    w = __builtin_amdgcn_cvt_pk_fp8_f32(bb.x, bb.y, 0, false);
    w = __builtin_amdgcn_cvt_pk_fp8_f32(bb.z, bb.w, w, true);
    r.y = (unsigned)w;
    w = __builtin_amdgcn_cvt_pk_fp8_f32(c4.x, c4.y, 0, false);
    w = __builtin_amdgcn_cvt_pk_fp8_f32(c4.z, c4.w, w, true);
    r.z = (unsigned)w;
    w = __builtin_amdgcn_cvt_pk_fp8_f32(d.x, d.y, 0, false);
    w = __builtin_amdgcn_cvt_pk_fp8_f32(d.z, d.w, w, true);
    r.w = (unsigned)w;
    featfp8[gtid] = r;
  }

  // ---- scatter: 4 edges per thread, vectorized index loads ----
  if (gtid < N_EDGES / 4) {
    int4 s = src4[gtid];
    int4 d = dst4[gtid];
    int p;
    p = atomicAdd(&cnt[d.x], 1); if (p < CAPN) col[d.x * CAPN + p] = s.x;
    p = atomicAdd(&cnt[d.y], 1); if (p < CAPN) col[d.y * CAPN + p] = s.y;
    p = atomicAdd(&cnt[d.z], 1); if (p < CAPN) col[d.z * CAPN + p] = s.z;
    p = atomicAdd(&cnt[d.w], 1); if (p < CAPN) col[d.w * CAPN + p] = s.w;
  }
}

// ------- fused: per-tile fp8 gather (mean-feat -> LDS) + register-tiled GEMM.
//         All 256 lanes gather (4 lanes/node: 2 feat-halves x 2 edge-halves);
//         W1/self-feat staged in registers (issue-early/write-late) under the gather.
//         h1 = relu([feat|meanf] @ [W1s;W1n] + b1); t2(fp8) = h1@W2n; s2 = h1@W2s. -------
__global__ __launch_bounds__(256) void l1g_kernel(
    const float* __restrict__ feat, const uint4* __restrict__ featfp8,
    const int* __restrict__ cnt, const int* __restrict__ col,
    const float* __restrict__ W1s, const float* __restrict__ W1n,
    const float* __restrict__ b1,
    const float* __restrict__ W2n, const float* __restrict__ W2s,
    unsigned* __restrict__ t2f8, float* __restrict__ s2) {
  __shared__ float sA[64 * APITCH];   // A^T: rows 0..31 self-feat, 32..63 mean-feat; 17 KB
  __shared__ float sW[64 * 64];       // W: sW[k][c], 16 KB; phase 2 reuses as [64][32]

  int t = threadIdx.x;
  int tile = blockIdx.x * 64;
  int nvalid = min(64, N_NODES - tile);

  // ---- T14 register staging: issue self-feat + W1 loads NOW, write to LDS later ----
  const float4* Fg = (const float4*)(feat + (size_t)tile * IN_F);
  int lim = nvalid * 8;
  int fi0 = t, fi1 = t + 256;
  float4 fa0, fa1;
  if (fi0 < lim) fa0 = Fg[fi0];
  if (fi1 < lim) fa1 = Fg[fi1];
  float4 wv[4];
#pragma unroll
  for (int it = 0; it < 4; ++it) {
    int idx = t + 256 * it;            // 0..1023
    int row = idx >> 4;
    const float4* srcw = (row < 32) ? (const float4*)W1s : (const float4*)W1n;
    wv[it] = srcw[(row & 31) * 16 + (idx & 15)];
  }

  // ---- gather mean-features: 4 lanes/node (half edges each), fp8 16B loads ----
  {
    int nl = t >> 2, c = (t >> 1) & 1, hp = t & 1;
    int v = tile + nl;
    if (nl < nvalid) {
      int deg = cnt[v];
      int start = v * CAPN;
      int end = start + min(deg, CAPN);
      float s[16];
#pragma unroll
      for (int j = 0; j < 16; ++j) s[j] = 0.0f;
      int e = start + hp;
      for (; e + 6 < end; e += 8) {
        uint4 q0 = featfp8[col[e] * 2 + c];
        uint4 q1 = featfp8[col[e + 2] * 2 + c];
        uint4 q2 = featfp8[col[e + 4] * 2 + c];
        uint4 q3 = featfp8[col[e + 6] * 2 + c];
        ADDQ(s, q0);
        ADDQ(s, q1);
        ADDQ(s, q2);
        ADDQ(s, q3);
      }
      for (; e < end; e += 2) {
        uint4 q = featfp8[col[e] * 2 + c];
        ADDQ(s, q);
      }
      // pair-reduce edge halves (partner = t^1, same wave)
#pragma unroll
      for (int j = 0; j < 16; ++j) s[j] += __shfl_xor(s[j], 1);
      float inv = 1.0f / fmaxf((float)deg, 1.0f);
      int j0 = 8 * hp;                 // split the 16 LDS writes across the pair
#pragma unroll
      for (int j = 0; j < 8; ++j)
        sA[(32 + 16 * c + j0 + j) * APITCH + nl] = s[j0 + j] * inv;   // meanf^T
    }
  }

  // ---- write staged registers to LDS (loads completed under the gather) ----
  if (fi0 < lim) {
    int n = fi0 >> 3, c8 = fi0 & 7;
    sA[(4 * c8 + 0) * APITCH + n] = fa0.x;
    sA[(4 * c8 + 1) * APITCH + n] = fa0.y;
    sA[(4 * c8 + 2) * APITCH + n] = fa0.z;
    sA[(4 * c8 + 3) * APITCH + n] = fa0.w;
  }
  if (fi1 < lim) {
    int n = fi1 >> 3, c8 = fi1 & 7;
    sA[(4 * c8 + 0) * APITCH + n] = fa1.x;
    sA[(4 * c8 + 1) * APITCH + n] = fa1.y;
    sA[(4 * c8 + 2) * APITCH + n] = fa1.z;
    sA[(4 * c8 + 3) * APITCH + n] = fa1.w;
  }
  {
    float4* Ws = (float4*)sW;
#pragma unroll
    for (int it = 0; it < 4; ++it) Ws[t + 256 * it] = wv[it];
  }

  int tx = t & 15, ty = t >> 4;
  int n0 = 4 * ty, c0 = 4 * tx;
  float4 bb = ((const float4*)b1)[tx];
  __syncthreads();

  // ---- phase 1: 4x4 register tile GEMM ----
  float acc[4][4];
#pragma unroll
  for (int i = 0; i < 4; ++i) { acc[i][0] = bb.x; acc[i][1] = bb.y; acc[i][2] = bb.z; acc[i][3] = bb.w; }
#pragma unroll 4
  for (int k = 0; k < 64; ++k) {
    float4 a = *(const float4*)&sA[k * APITCH + n0];
    float4 w = *(const float4*)&sW[k * 64 + c0];
    acc[0][0] += a.x * w.x; acc[0][1] += a.x * w.y; acc[0][2] += a.x * w.z; acc[0][3] += a.x * w.w;
    acc[1][0] += a.y * w.x; acc[1][1] += a.y * w.y; acc[1][2] += a.y * w.z; acc[1][3] += a.y * w.w;
    acc[2][0] += a.z * w.x; acc[2][1] += a.z * w.y; acc[2][2] += a.z * w.z; acc[2][3] += a.z * w.w;
    acc[3][0] += a.w * w.x; acc[3][1] += a.w * w.y; acc[3][2] += a.w * w.z; acc[3][3] += a.w * w.w;
  }
  __syncthreads();

  // ---- write h1^T (relu) back into sA; restage W2cat ----
#pragma unroll
  for (int jj = 0; jj < 4; ++jj) {
    float4 v;
    v.x = fmaxf(acc[0][jj], 0.0f);
    v.y = fmaxf(acc[1][jj], 0.0f);
    v.z = fmaxf(acc[2][jj], 0.0f);
    v.w = fmaxf(acc[3][jj], 0.0f);
    *(float4*)&sA[(c0 + jj) * APITCH + n0] = v;
  }
  {
    float4* Ws = (float4*)sW;
#pragma unroll
    for (int it = 0; it < 2; ++it) {
      int idx = t + 256 * it;
      int row = idx >> 3, ch = idx & 7;
      const float4* srcw = (ch < 4) ? (const float4*)W2n : (const float4*)W2s;
      Ws[row * 8 + ch] = srcw[row * 4 + (ch & 3)];
    }
  }
  __syncthreads();

  // ---- phase 2: 4 nodes x 2 cols per thread; t2 stored as fp8 pairs ----
  int c2 = 2 * tx;
  float a0 = 0.f, a1 = 0.f, b0 = 0.f, b1_ = 0.f, d0 = 0.f, d1 = 0.f, e0 = 0.f, e1 = 0.f;
#pragma unroll 4
  for (int k = 0; k < 64; ++k) {
    float4 a = *(const float4*)&sA[k * APITCH + n0];
    float2 w = *(const float2*)&sW[k * 32 + c2];
    a0 += a.x * w.x; a1 += a.x * w.y;
    b0 += a.y * w.x; b1_ += a.y * w.y;
    d0 += a.z * w.x; d1 += a.z * w.y;
    e0 += a.w * w.x; e1 += a.w * w.y;
  }
  {
    float rs[4][2] = {{a0, a1}, {b0, b1_}, {d0, d1}, {e0, e1}};
    int cc = c2 & 15;
#pragma unroll
    for (int i = 0; i < 4; ++i) {
      int v = tile + n0 + i;
      if (v < N_NODES) {
        if (c2 < 16) {
          int w = __builtin_amdgcn_cvt_pk_fp8_f32(rs[i][0], rs[i][1], 0, false);
          *(unsigned short*)((char*)t2f8 + (size_t)v * 16 + cc) = (unsigned short)w;
        } else {
          *(float2*)&s2[v * OUT_F + cc] = make_float2(rs[i][0], rs[i][1]);
        }
      }
    }
  }
}

// ------- layer 2 aggregate + final: fp8 gather, 2 lanes/node (edge-split + pair reduce) -------
__global__ __launch_bounds__(256) void gather2_final_kernel(
    const int* __restrict__ cnt, const int* __restrict__ col,
    const uint4* __restrict__ t2f8, const float* __restrict__ s2,
    const float* __restrict__ b2, float* __restrict__ out) {
  int g = blockIdx.x * 256 + threadIdx.x;
  int v = g >> 1, hp = g & 1;
  if (v >= N_NODES) return;
  int deg = cnt[v];
  int start = v * CAPN;
  int end = start + min(deg, CAPN);
  float s[16];
#pragma unroll
  for (int j = 0; j < 16; ++j) s[j] = 0.0f;
  int e = start + hp;
  for (; e + 6 < end; e += 8) {
    uint4 q0 = t2f8[col[e]];
    uint4 q1 = t2f8[col[e + 2]];
    uint4 q2 = t2f8[col[e + 4]];
    uint4 q3 = t2f8[col[e + 6]];
    ADDQ(s, q0);
    ADDQ(s, q1);
    ADDQ(s, q2);
    ADDQ(s, q3);
  }
  for (; e < end; e += 2) {
    uint4 q = t2f8[col[e]];
    ADDQ(s, q);
  }
  // pair-reduce (partner = g^1, same wave, same v)
#pragma unroll
  for (int j = 0; j < 16; ++j) s[j] += __shfl_xor(s[j], 1);
  float inv = 1.0f / fmaxf((float)deg, 1.0f);
  const float4* S = (const float4*)s2;
  const float4* B = (const float4*)b2;
  float4* O = (float4*)out;
#pragma unroll
  for (int i = 0; i < 2; ++i) {
    int ii = 2 * hp + i;               // pair splits the 4 float4 stores
    float4 sv = S[v * 4 + ii];
    float4 bv = B[ii];
    float4 r;
    r.x = sv.x + bv.x + s[4 * ii + 0] * inv;
    r.y = sv.y + bv.y + s[4 * ii + 1] * inv;
    r.z = sv.z + bv.z + s[4 * ii + 2] * inv;
    r.w = sv.w + bv.w + s[4 * ii + 3] * inv;
    O[v * 4 + ii] = r;
  }
}

extern "C" void kernel_launch(void* const* d_in, const int* in_sizes, int n_in,
                              void* d_out, int out_size, void* d_ws, size_t ws_size,
                              hipStream_t stream) {
  const float* feat = (const float*)d_in[0];
  const int* src    = (const int*)d_in[1];
  const int* dst    = (const int*)d_in[2];
  const float* W1s  = (const float*)d_in[3];
  const float* W1n  = (const float*)d_in[4];
  const float* b1   = (const float*)d_in[5];
  const float* W2s  = (const float*)d_in[6];
  const float* W2n  = (const float*)d_in[7];
  const float* b2   = (const float*)d_in[8];
  float* out = (float*)d_out;

  const size_t N = N_NODES;
  // workspace layout (~31 MB, all 16B-aligned offsets)
  int* cnt = (int*)d_ws;                          // N ints (400 KB)
  unsigned* featfp8 = (unsigned*)(cnt + N);       // 8N uints (32N fp8, 3.2 MB)
  unsigned* t2f8 = featfp8 + 8 * N;               // 4N uints (16N fp8, 1.6 MB)
  float* s2 = (float*)(t2f8 + 4 * N);             // 16N fp32 (6.4 MB)
  int* col = (int*)(s2 + 16 * N);                 // N*CAPN ints (19.2 MB arena)

  zero_cnt_kernel<<<(N_NODES / 4 + 255) / 256, 256, 0, stream>>>((uint4*)cnt);
  scatter_kernel<<<(N_EDGES / 4 + 255) / 256, 256, 0, stream>>>(
      (const int4*)src, (const int4*)dst, (const float4*)feat, cnt, col, (uint4*)featfp8);
  l1g_kernel<<<(N_NODES + 63) / 64, 256, 0, stream>>>(
      feat, (const uint4*)featfp8, cnt, col, W1s, W1n, b1, W2n, W2s, t2f8, s2);
  gather2_final_kernel<<<(2 * N_NODES + 255) / 256, 256, 0, stream>>>(
      cnt, col, (const uint4*)t2f8, s2, b2, out);
}

// Round 3
// 161.676 us; speedup vs baseline: 1.6994x; 1.6994x over previous
//
#include <hip/hip_runtime.h>

#define N_NODES 100000
#define N_EDGES 1600000
#define IN_F 32
#define HID_F 64
#define OUT_F 16
#define BSIZE 512                    // nodes per bucket (bucket = dst >> 9)
#define NBKT 256                     // scan width in bucket_kernel (196 used)
#define CAP 10240                    // edge capacity per bucket slab (mean 8192, >20 sd margin)
#define CHUNK 4096                   // edges per block in bucket-sort pass
#define NBUCK ((N_NODES + BSIZE - 1) / BSIZE)   // 196
#define CAPN 48                      // per-node arena capacity (Poisson(16); P(deg>=48)~1e-9/node)
#define APITCH 68                    // padded pitch for transposed A / h1 tiles

using f2v = __attribute__((ext_vector_type(2))) float;

// accumulate 16 fp8-e4m3 (packed in uint4 Q, HW decode) into 16 fp32 accumulators
#define ADDQ(s, Q) do { f2v p_; \
  p_ = __builtin_amdgcn_cvt_pk_f32_fp8((int)(Q).x, false); s[0] += p_[0]; s[1] += p_[1]; \
  p_ = __builtin_amdgcn_cvt_pk_f32_fp8((int)(Q).x, true);  s[2] += p_[0]; s[3] += p_[1]; \
  p_ = __builtin_amdgcn_cvt_pk_f32_fp8((int)(Q).y, false); s[4] += p_[0]; s[5] += p_[1]; \
  p_ = __builtin_amdgcn_cvt_pk_f32_fp8((int)(Q).y, true);  s[6] += p_[0]; s[7] += p_[1]; \
  p_ = __builtin_amdgcn_cvt_pk_f32_fp8((int)(Q).z, false); s[8] += p_[0]; s[9] += p_[1]; \
  p_ = __builtin_amdgcn_cvt_pk_f32_fp8((int)(Q).z, true);  s[10] += p_[0]; s[11] += p_[1]; \
  p_ = __builtin_amdgcn_cvt_pk_f32_fp8((int)(Q).w, false); s[12] += p_[0]; s[13] += p_[1]; \
  p_ = __builtin_amdgcn_cvt_pk_f32_fp8((int)(Q).w, true);  s[14] += p_[0]; s[15] += p_[1]; \
} while (0)

// ---------------- slab cursor init ----------------
__global__ __launch_bounds__(NBKT) void cursor_init_kernel(int* __restrict__ cursor) {
  cursor[threadIdx.x] = threadIdx.x * CAP;
}

// ---- one-pass LDS-staged bucket sort; packed (src<<9)|dstLocal. Wave-shfl scan (2 barriers
//      instead of 16). Absorbs feat -> fp8 e4m3 conversion (200,192 threads >= 200,000 items). ----
__global__ __launch_bounds__(512) void bucket_kernel(
    const int* __restrict__ src, const int* __restrict__ dst,
    const float4* __restrict__ featin, uint4* __restrict__ featfp8,
    int* __restrict__ cursor, unsigned* __restrict__ sorted) {
  __shared__ unsigned stage[CHUNK];        // 16 KB
  __shared__ unsigned char sbkt[CHUNK];    // 4 KB
  __shared__ int lcnt[NBKT], lscan[NBKT], gbase[NBKT];
  __shared__ int wsum[4];
  int t = threadIdx.x;

  // ---- absorbed conversion: feat -> fp8 e4m3 (16 floats per thread, independent work) ----
  {
    int gtid = blockIdx.x * 512 + t;
    if (gtid < N_NODES * IN_F / 16) {
      float4 a = featin[4 * gtid], bb = featin[4 * gtid + 1];
      float4 c4 = featin[4 * gtid + 2], d = featin[4 * gtid + 3];
      uint4 r;
      int w;
      w = __builtin_amdgcn_cvt_pk_fp8_f32(a.x, a.y, 0, false);
      w = __builtin_amdgcn_cvt_pk_fp8_f32(a.z, a.w, w, true);
      r.x = (unsigned)w;
      w = __builtin_amdgcn_cvt_pk_fp8_f32(bb.x, bb.y, 0, false);
      w = __builtin_amdgcn_cvt_pk_fp8_f32(bb.z, bb.w, w, true);
      r.y = (unsigned)w;
      w = __builtin_amdgcn_cvt_pk_fp8_f32(c4.x, c4.y, 0, false);
      w = __builtin_amdgcn_cvt_pk_fp8_f32(c4.z, c4.w, w, true);
      r.z = (unsigned)w;
      w = __builtin_amdgcn_cvt_pk_fp8_f32(d.x, d.y, 0, false);
      w = __builtin_amdgcn_cvt_pk_fp8_f32(d.z, d.w, w, true);
      r.w = (unsigned)w;
      featfp8[gtid] = r;
    }
  }

  if (t < NBKT) lcnt[t] = 0;
  __syncthreads();

  int base = blockIdx.x * CHUNK;
  unsigned mypk[CHUNK / 512];
  int myb[CHUNK / 512], myrank[CHUNK / 512];
#pragma unroll
  for (int i = 0; i < CHUNK / 512; ++i) {
    int e = base + t + 512 * i;
    if (e < N_EDGES) {
      unsigned s = (unsigned)src[e], d = (unsigned)dst[e];
      myb[i] = (int)(d >> 9);
      mypk[i] = (s << 9) | (d & 511u);
      myrank[i] = atomicAdd(&lcnt[myb[i]], 1);
    } else {
      myb[i] = -1;
    }
  }
  __syncthreads();

  // ---- inclusive scan of lcnt[0..255] via wave shfl (threads 0..255 = waves 0..3) ----
  int x = 0;
  if (t < NBKT) {
    x = lcnt[t];
#pragma unroll
    for (int off = 1; off < 64; off <<= 1) {
      int y = __shfl_up(x, off);
      if ((t & 63) >= off) x += y;
    }
    if ((t & 63) == 63) wsum[t >> 6] = x;
  }
  __syncthreads();
  if (t < NBKT) {
    int w = t >> 6, add = 0;
    if (w > 0) add += wsum[0];
    if (w > 1) add += wsum[1];
    if (w > 2) add += wsum[2];
    lscan[t] = x + add;
    gbase[t] = lcnt[t] ? atomicAdd(&cursor[t], lcnt[t]) : 0;
  }
  __syncthreads();

#pragma unroll
  for (int i = 0; i < CHUNK / 512; ++i) {
    if (myb[i] >= 0) {
      int slot = (lscan[myb[i]] - lcnt[myb[i]]) + myrank[i];
      stage[slot] = mypk[i];
      sbkt[slot] = (unsigned char)myb[i];
    }
  }
  __syncthreads();
  int nvalid = min(CHUNK, N_EDGES - base);
  for (int i = t; i < nvalid; i += 512) {
    unsigned p = stage[i];
    int b = (int)sbkt[i];
    int addr = gbase[b] + (i - (lscan[b] - lcnt[b]));
    sorted[addr] = p;
  }
}

// ---- scan-free arena CSR: one block per bucket; LDS atomic ranks -> direct col writes.
//      All writes confined to this bucket's 96 KB col window (single-XCD L2 locality). ----
__global__ __launch_bounds__(1024) void csr_kernel(
    const unsigned* __restrict__ sorted, const int* __restrict__ cursor,
    int* __restrict__ cnt, int* __restrict__ col) {
  __shared__ int lcnt[BSIZE];
  int t = threadIdx.x;
  int b = blockIdx.x;
  if (t < BSIZE) lcnt[t] = 0;
  __syncthreads();

  int base = b * CAP;
  int ne = cursor[b] - base;
  for (int i = t; i < ne; i += 1024) {
    unsigned p = sorted[base + i];
    int d = (int)(p & (BSIZE - 1));
    int r = atomicAdd(&lcnt[d], 1);
    if (r < CAPN) col[(b * BSIZE + d) * CAPN + r] = (int)(p >> 9);
  }
  __syncthreads();
  if (t < BSIZE) {
    int v = b * BSIZE + t;
    if (v < N_NODES) cnt[v] = lcnt[t];   // true in-degree (mean divisor)
  }
}

// ------- fused: per-tile fp8 gather (mean-feat -> LDS) + register-tiled GEMM.
//         All 256 lanes gather (4 lanes/node: 2 feat-halves x 2 edge-halves);
//         W1/self-feat staged in registers (issue-early/write-late) under the gather.
//         h1 = relu([feat|meanf] @ [W1s;W1n] + b1); t2(fp8) = h1@W2n; s2 = h1@W2s. -------
__global__ __launch_bounds__(256) void l1g_kernel(
    const float* __restrict__ feat, const uint4* __restrict__ featfp8,
    const int* __restrict__ cnt, const int* __restrict__ col,
    const float* __restrict__ W1s, const float* __restrict__ W1n,
    const float* __restrict__ b1,
    const float* __restrict__ W2n, const float* __restrict__ W2s,
    unsigned* __restrict__ t2f8, float* __restrict__ s2) {
  __shared__ float sA[64 * APITCH];   // A^T: rows 0..31 self-feat, 32..63 mean-feat; 17 KB
  __shared__ float sW[64 * 64];       // W: sW[k][c], 16 KB; phase 2 reuses as [64][32]

  int t = threadIdx.x;
  int tile = blockIdx.x * 64;
  int nvalid = min(64, N_NODES - tile);

  // ---- T14 register staging: issue self-feat + W1 loads NOW, write to LDS later ----
  const float4* Fg = (const float4*)(feat + (size_t)tile * IN_F);
  int lim = nvalid * 8;
  int fi0 = t, fi1 = t + 256;
  float4 fa0, fa1;
  if (fi0 < lim) fa0 = Fg[fi0];
  if (fi1 < lim) fa1 = Fg[fi1];
  float4 wv[4];
#pragma unroll
  for (int it = 0; it < 4; ++it) {
    int idx = t + 256 * it;            // 0..1023
    int row = idx >> 4;
    const float4* srcw = (row < 32) ? (const float4*)W1s : (const float4*)W1n;
    wv[it] = srcw[(row & 31) * 16 + (idx & 15)];
  }

  // ---- gather mean-features: 4 lanes/node (half edges each), fp8 16B loads ----
  {
    int nl = t >> 2, c = (t >> 1) & 1, hp = t & 1;
    int v = tile + nl;
    if (nl < nvalid) {
      int deg = cnt[v];
      int start = v * CAPN;
      int end = start + min(deg, CAPN);
      float s[16];
#pragma unroll
      for (int j = 0; j < 16; ++j) s[j] = 0.0f;
      int e = start + hp;
      for (; e + 6 < end; e += 8) {
        uint4 q0 = featfp8[col[e] * 2 + c];
        uint4 q1 = featfp8[col[e + 2] * 2 + c];
        uint4 q2 = featfp8[col[e + 4] * 2 + c];
        uint4 q3 = featfp8[col[e + 6] * 2 + c];
        ADDQ(s, q0);
        ADDQ(s, q1);
        ADDQ(s, q2);
        ADDQ(s, q3);
      }
      for (; e < end; e += 2) {
        uint4 q = featfp8[col[e] * 2 + c];
        ADDQ(s, q);
      }
      // pair-reduce edge halves (partner = t^1, same wave)
#pragma unroll
      for (int j = 0; j < 16; ++j) s[j] += __shfl_xor(s[j], 1);
      float inv = 1.0f / fmaxf((float)deg, 1.0f);
      int j0 = 8 * hp;                 // split the 16 LDS writes across the pair
#pragma unroll
      for (int j = 0; j < 8; ++j)
        sA[(32 + 16 * c + j0 + j) * APITCH + nl] = s[j0 + j] * inv;   // meanf^T
    }
  }

  // ---- write staged registers to LDS (loads completed under the gather) ----
  if (fi0 < lim) {
    int n = fi0 >> 3, c8 = fi0 & 7;
    sA[(4 * c8 + 0) * APITCH + n] = fa0.x;
    sA[(4 * c8 + 1) * APITCH + n] = fa0.y;
    sA[(4 * c8 + 2) * APITCH + n] = fa0.z;
    sA[(4 * c8 + 3) * APITCH + n] = fa0.w;
  }
  if (fi1 < lim) {
    int n = fi1 >> 3, c8 = fi1 & 7;
    sA[(4 * c8 + 0) * APITCH + n] = fa1.x;
    sA[(4 * c8 + 1) * APITCH + n] = fa1.y;
    sA[(4 * c8 + 2) * APITCH + n] = fa1.z;
    sA[(4 * c8 + 3) * APITCH + n] = fa1.w;
  }
  {
    float4* Ws = (float4*)sW;
#pragma unroll
    for (int it = 0; it < 4; ++it) Ws[t + 256 * it] = wv[it];
  }

  int tx = t & 15, ty = t >> 4;
  int n0 = 4 * ty, c0 = 4 * tx;
  float4 bb = ((const float4*)b1)[tx];
  __syncthreads();

  // ---- phase 1: 4x4 register tile GEMM ----
  float acc[4][4];
#pragma unroll
  for (int i = 0; i < 4; ++i) { acc[i][0] = bb.x; acc[i][1] = bb.y; acc[i][2] = bb.z; acc[i][3] = bb.w; }
#pragma unroll 4
  for (int k = 0; k < 64; ++k) {
    float4 a = *(const float4*)&sA[k * APITCH + n0];
    float4 w = *(const float4*)&sW[k * 64 + c0];
    acc[0][0] += a.x * w.x; acc[0][1] += a.x * w.y; acc[0][2] += a.x * w.z; acc[0][3] += a.x * w.w;
    acc[1][0] += a.y * w.x; acc[1][1] += a.y * w.y; acc[1][2] += a.y * w.z; acc[1][3] += a.y * w.w;
    acc[2][0] += a.z * w.x; acc[2][1] += a.z * w.y; acc[2][2] += a.z * w.z; acc[2][3] += a.z * w.w;
    acc[3][0] += a.w * w.x; acc[3][1] += a.w * w.y; acc[3][2] += a.w * w.z; acc[3][3] += a.w * w.w;
  }
  __syncthreads();

  // ---- write h1^T (relu) back into sA; restage W2cat ----
#pragma unroll
  for (int jj = 0; jj < 4; ++jj) {
    float4 v;
    v.x = fmaxf(acc[0][jj], 0.0f);
    v.y = fmaxf(acc[1][jj], 0.0f);
    v.z = fmaxf(acc[2][jj], 0.0f);
    v.w = fmaxf(acc[3][jj], 0.0f);
    *(float4*)&sA[(c0 + jj) * APITCH + n0] = v;
  }
  {
    float4* Ws = (float4*)sW;
#pragma unroll
    for (int it = 0; it < 2; ++it) {
      int idx = t + 256 * it;
      int row = idx >> 3, ch = idx & 7;
      const float4* srcw = (ch < 4) ? (const float4*)W2n : (const float4*)W2s;
      Ws[row * 8 + ch] = srcw[row * 4 + (ch & 3)];
    }
  }
  __syncthreads();

  // ---- phase 2: 4 nodes x 2 cols per thread; t2 stored as fp8 pairs ----
  int c2 = 2 * tx;
  float a0 = 0.f, a1 = 0.f, b0 = 0.f, b1_ = 0.f, d0 = 0.f, d1 = 0.f, e0 = 0.f, e1 = 0.f;
#pragma unroll 4
  for (int k = 0; k < 64; ++k) {
    float4 a = *(const float4*)&sA[k * APITCH + n0];
    float2 w = *(const float2*)&sW[k * 32 + c2];
    a0 += a.x * w.x; a1 += a.x * w.y;
    b0 += a.y * w.x; b1_ += a.y * w.y;
    d0 += a.z * w.x; d1 += a.z * w.y;
    e0 += a.w * w.x; e1 += a.w * w.y;
  }
  {
    float rs[4][2] = {{a0, a1}, {b0, b1_}, {d0, d1}, {e0, e1}};
    int cc = c2 & 15;
#pragma unroll
    for (int i = 0; i < 4; ++i) {
      int v = tile + n0 + i;
      if (v < N_NODES) {
        if (c2 < 16) {
          int w = __builtin_amdgcn_cvt_pk_fp8_f32(rs[i][0], rs[i][1], 0, false);
          *(unsigned short*)((char*)t2f8 + (size_t)v * 16 + cc) = (unsigned short)w;
        } else {
          *(float2*)&s2[v * OUT_F + cc] = make_float2(rs[i][0], rs[i][1]);
        }
      }
    }
  }
}

// ------- layer 2 aggregate + final: fp8 gather, 2 lanes/node (edge-split + pair reduce) -------
__global__ __launch_bounds__(256) void gather2_final_kernel(
    const int* __restrict__ cnt, const int* __restrict__ col,
    const uint4* __restrict__ t2f8, const float* __restrict__ s2,
    const float* __restrict__ b2, float* __restrict__ out) {
  int g = blockIdx.x * 256 + threadIdx.x;
  int v = g >> 1, hp = g & 1;
  if (v >= N_NODES) return;
  int deg = cnt[v];
  int start = v * CAPN;
  int end = start + min(deg, CAPN);
  float s[16];
#pragma unroll
  for (int j = 0; j < 16; ++j) s[j] = 0.0f;
  int e = start + hp;
  for (; e + 6 < end; e += 8) {
    uint4 q0 = t2f8[col[e]];
    uint4 q1 = t2f8[col[e + 2]];
    uint4 q2 = t2f8[col[e + 4]];
    uint4 q3 = t2f8[col[e + 6]];
    ADDQ(s, q0);
    ADDQ(s, q1);
    ADDQ(s, q2);
    ADDQ(s, q3);
  }
  for (; e < end; e += 2) {
    uint4 q = t2f8[col[e]];
    ADDQ(s, q);
  }
  // pair-reduce (partner = g^1, same wave, same v)
#pragma unroll
  for (int j = 0; j < 16; ++j) s[j] += __shfl_xor(s[j], 1);
  float inv = 1.0f / fmaxf((float)deg, 1.0f);
  const float4* S = (const float4*)s2;
  const float4* B = (const float4*)b2;
  float4* O = (float4*)out;
#pragma unroll
  for (int i = 0; i < 2; ++i) {
    int ii = 2 * hp + i;               // pair splits the 4 float4 stores
    float4 sv = S[v * 4 + ii];
    float4 bv = B[ii];
    float4 r;
    r.x = sv.x + bv.x + s[4 * ii + 0] * inv;
    r.y = sv.y + bv.y + s[4 * ii + 1] * inv;
    r.z = sv.z + bv.z + s[4 * ii + 2] * inv;
    r.w = sv.w + bv.w + s[4 * ii + 3] * inv;
    O[v * 4 + ii] = r;
  }
}

extern "C" void kernel_launch(void* const* d_in, const int* in_sizes, int n_in,
                              void* d_out, int out_size, void* d_ws, size_t ws_size,
                              hipStream_t stream) {
  const float* feat = (const float*)d_in[0];
  const int* src    = (const int*)d_in[1];
  const int* dst    = (const int*)d_in[2];
  const float* W1s  = (const float*)d_in[3];
  const float* W1n  = (const float*)d_in[4];
  const float* b1   = (const float*)d_in[5];
  const float* W2s  = (const float*)d_in[6];
  const float* W2n  = (const float*)d_in[7];
  const float* b2   = (const float*)d_in[8];
  float* out = (float*)d_out;

  const size_t N = N_NODES;
  const size_t SLAB = (size_t)NBUCK * CAP;        // 2,007,040 entries (8.03 MB)
  // workspace layout (~32.4 MB): s2 overlays sorted (sorted dead after csr_kernel)
  int* cnt = (int*)d_ws;                          // N ints (400 KB)
  int* col = cnt + N + 16;                        // N*CAPN ints (19.2 MB arena)
  unsigned* sorted = (unsigned*)(col + N * CAPN + 16);  // SLAB uint32 (8.03 MB)
  float* s2 = (float*)sorted;                     // 16N fp32 (6.4 MB) — union with sorted
  unsigned* featfp8 = (unsigned*)(sorted + SLAB + 16);  // 8N uints (3.2 MB)
  unsigned* t2f8 = featfp8 + 8 * N;               // 4N uints (1.6 MB)
  int* cursor = (int*)(t2f8 + 4 * N);             // NBKT ints

  cursor_init_kernel<<<1, NBKT, 0, stream>>>(cursor);
  bucket_kernel<<<(N_EDGES + CHUNK - 1) / CHUNK, 512, 0, stream>>>(
      src, dst, (const float4*)feat, (uint4*)featfp8, cursor, sorted);
  csr_kernel<<<NBUCK, 1024, 0, stream>>>(sorted, cursor, cnt, col);
  l1g_kernel<<<(N_NODES + 63) / 64, 256, 0, stream>>>(
      feat, (const uint4*)featfp8, cnt, col, W1s, W1n, b1, W2n, W2s, t2f8, s2);
  gather2_final_kernel<<<(2 * N_NODES + 255) / 256, 256, 0, stream>>>(
      cnt, col, (const uint4*)t2f8, s2, b2, out);
}